// Round 19
// baseline (2237.387 us; speedup 1.0000x reference)
//
#include <hip/hip_runtime.h>
#include <math.h>

#define BATCH 4096
#define NIN   4096
#define NOUT  4096
#define NSTAGE32 128            // stages of BK=32 (hyb fallback / base kernel)
// R9-verified ACID ORDER (frozen): [512x8] k-panels, single ascending fmaf
// chain, fold every 512 k, f32 epilogue. BASE on MFMA pipe (R13-verified).
// R19: SPLIT kernels. Fusion forced VGPR 128+64(acc)=192 -> 2 waves/SIMD.
// Split: base MFMA kernel (LDS-free, global frags) + acid VALU kernel
// (ca/ma only ~148 regs -> 3 waves/SIMD; all staging via global_load_lds,
// BK=16 dbuf 32KB -> 3 blocks/CU, zero ds_writes, zero staging VALU).

typedef __attribute__((ext_vector_type(8))) short bf16x8;
typedef __attribute__((ext_vector_type(8))) unsigned short u16x8;
typedef __attribute__((ext_vector_type(4))) float f32x4;

__device__ __forceinline__ float2 compute_terms(float xv) {
    float h  = (float)exp10(-(double)xv);
    float oh = 1e-14f / h;
    return make_float2(h * 0.1f, oh * 0.1f);
}
__device__ __forceinline__ unsigned short bf16_rne(float v) {
    unsigned int b = __float_as_uint(v);
    return (unsigned short)((b + 0x7FFFu + ((b >> 16) & 1u)) >> 16);
}
__device__ __forceinline__ float signf_of(float wv) {
    return (wv > 0.f) ? 1.f : ((wv < 0.f) ? -1.f : 0.f);
}
__device__ __forceinline__ unsigned short signbf16_of(float wv) {
    return (wv > 0.f) ? 0x3F80u : ((wv < 0.f) ? 0xBF80u : 0u);
}

#define GLOAD16(g, l)                                                        \
    __builtin_amdgcn_global_load_lds(                                        \
        (const __attribute__((address_space(1))) void*)(g),                  \
        (__attribute__((address_space(3))) void*)(l), 16, 0, 0)

// --- precompute A: acid f32 TRANSPOSED AaT[k][m] (LDS-tiled) + base bf16 Ab[m][k] ---
__global__ __launch_bounds__(256) void precompute_A(const float* __restrict__ x,
                                                    float* __restrict__ aaT,
                                                    unsigned short* __restrict__ ab) {
    __shared__ float tile[64][65];
    const int m0 = blockIdx.y * 64, k0 = blockIdx.x * 64;
    const int tid = threadIdx.x;
    #pragma unroll
    for (int it = 0; it < 4; ++it) {
        int idx = tid + it * 256;
        int row = idx >> 4, q = idx & 15;
        float4 xv = *(const float4*)(x + (size_t)(m0 + row) * NIN + k0 + q * 4);
        float2 t0 = compute_terms(xv.x), t1 = compute_terms(xv.y),
               t2 = compute_terms(xv.z), t3 = compute_terms(xv.w);
        *(ushort4*)(ab + (size_t)(m0 + row) * NIN + k0 + q * 4) =
            make_ushort4(bf16_rne(t0.y), bf16_rne(t1.y), bf16_rne(t2.y), bf16_rne(t3.y));
        tile[row][q * 4 + 0] = t0.x; tile[row][q * 4 + 1] = t1.x;
        tile[row][q * 4 + 2] = t2.x; tile[row][q * 4 + 3] = t3.x;
    }
    __syncthreads();
    #pragma unroll
    for (int it = 0; it < 4; ++it) {
        int idx = tid + it * 256;
        int krow = idx >> 4, q = idx & 15;
        float4 v = make_float4(tile[q * 4 + 0][krow], tile[q * 4 + 1][krow],
                               tile[q * 4 + 2][krow], tile[q * 4 + 3][krow]);
        *(float4*)(aaT + (size_t)(k0 + krow) * NIN + m0 + q * 4) = v;
    }
}

// --- precompute W: sign bf16 TRANSPOSED signT[n][k] + sign f32 signF[k][n] ---
__global__ __launch_bounds__(256) void precompute_signTF(const float* __restrict__ w,
                                                         unsigned short* __restrict__ sT,
                                                         float* __restrict__ sF) {
    __shared__ unsigned short tile[64][68];
    const int k0 = blockIdx.y * 64, n0 = blockIdx.x * 64;
    const int tid = threadIdx.x;
    #pragma unroll
    for (int it = 0; it < 4; ++it) {
        int idx = tid + it * 256;
        int krow = idx >> 4, q = idx & 15;
        float4 wv = *(const float4*)(w + (size_t)(k0 + krow) * NOUT + n0 + q * 4);
        *(ushort4*)&tile[krow][q * 4] =
            make_ushort4(signbf16_of(wv.x), signbf16_of(wv.y), signbf16_of(wv.z), signbf16_of(wv.w));
        *(float4*)(sF + (size_t)(k0 + krow) * NOUT + n0 + q * 4) =
            make_float4(signf_of(wv.x), signf_of(wv.y), signf_of(wv.z), signf_of(wv.w));
    }
    __syncthreads();
    #pragma unroll
    for (int it = 0; it < 2; ++it) {
        int idx = tid + it * 256;
        int n = idx >> 3, kc = idx & 7;
        u16x8 v;
        #pragma unroll
        for (int j = 0; j < 8; ++j) v[j] = tile[kc * 8 + j][n];
        *(u16x8*)(sT + (size_t)(n0 + n) * NIN + k0 + kc * 8) = v;
    }
}

// --- base GEMM: standalone MFMA kernel, LDS-free loads (L2-resident operands) ---
__global__ __launch_bounds__(256) void base_gemm(const unsigned short* __restrict__ Ab,
                                                 const unsigned short* __restrict__ SignT,
                                                 float* __restrict__ BaseW) {
    __shared__ float BoutH[128][68];   // 34816 B, epilogue only
    const int tid  = threadIdx.x;
    const int lane = tid & 63;
    const int wv   = tid >> 6;
    const int g    = lane >> 4;
    const int r16  = lane & 15;
    const int tx   = tid & 15;
    const int ty   = tid >> 4;
    const int bm0  = blockIdx.y * 128;
    const int bn0  = blockIdx.x * 128;

    f32x4 acc[2][8] = {};

    for (int s = 0; s < NSTAGE32; ++s) {
        const int k0 = s * 32;
        bf16x8 af0 = *(const bf16x8*)(Ab + (size_t)(bm0 + wv * 32 +      r16) * NIN + k0 + g * 8);
        bf16x8 af1 = *(const bf16x8*)(Ab + (size_t)(bm0 + wv * 32 + 16 + r16) * NIN + k0 + g * 8);
        #pragma unroll
        for (int tc = 0; tc < 8; ++tc) {
            bf16x8 bf = *(const bf16x8*)(SignT + (size_t)(bn0 + tc * 16 + r16) * NIN + k0 + g * 8);
            acc[0][tc] = __builtin_amdgcn_mfma_f32_16x16x32_bf16(af0, bf, acc[0][tc], 0, 0, 0);
            acc[1][tc] = __builtin_amdgcn_mfma_f32_16x16x32_bf16(af1, bf, acc[1][tc], 0, 0, 0);
        }
    }

    // two-half combine (R15/R18-verified layout) -> BaseW f32
    #pragma unroll
    for (int hh = 0; hh < 2; ++hh) {
        #pragma unroll
        for (int tr = 0; tr < 2; ++tr)
            #pragma unroll
            for (int tc = 0; tc < 4; ++tc)
                #pragma unroll
                for (int rr = 0; rr < 4; ++rr)
                    BoutH[wv * 32 + tr * 16 + g * 4 + rr][tc * 16 + r16] = acc[tr][hh * 4 + tc][rr];
        __syncthreads();
        #pragma unroll
        for (int m = 0; m < 8; ++m) {
            int row = ty * 8 + m;
            float4 bv = *(const float4*)&BoutH[row][tx * 4];
            *(float4*)(BaseW + (size_t)(bm0 + row) * NOUT + bn0 + hh * 64 + tx * 4) = bv;
        }
        __syncthreads();
    }
}

// --- acid GEMM: pure-VALU chain, glds-staged, 3 waves/SIMD ---
// LDS: As[2][16][128] + Bs[2][16][128] f32 = 32768 B -> 3 blocks/CU.
// Regs: ca 64 + ma 64 + addr ~20 = ~148 <= 170 -> launch_bounds(256,3) safe
// (R12/R16 law: only force min-waves when footprint fits).
__global__ __launch_bounds__(256, 3) void acid_gemm_valu(const float* __restrict__ AaT,
                                                         const float* __restrict__ SignF,
                                                         const float* __restrict__ BaseW,
                                                         float* __restrict__ out) {
    __shared__ __align__(16) float As[2][16][128];
    __shared__ __align__(16) float Bs[2][16][128];

    const int tid = threadIdx.x;
    const int tx  = tid & 15;      // cols tx*4..+3 and 64+tx*4..+3
    const int ty  = tid >> 4;      // rows ty*8..+7
    const int w   = tid >> 6;      // wave
    const int l   = tid & 63;
    const int bm0 = blockIdx.y * 128;
    const int bn0 = blockIdx.x * 128;

    const int lrow = (l >> 5);       // sub-row within a 1024B glds
    const int lcol = (l & 31) * 4;   // f32 col within 128-wide row

    float ma[8][8] = {}, ca[8][8] = {};

    // stage s (BK=16): 4 waves x 4 rows each; 2 rows per glds (1024 B)
    #define AISSUE(s, b)                                                            \
        {                                                                           \
            const int k0_ = (s) * 16;                                               \
            _Pragma("unroll")                                                       \
            for (int j = 0; j < 2; ++j) {                                           \
                const int kr_ = w * 4 + 2 * j;                                      \
                GLOAD16(AaT   + (size_t)(k0_ + kr_ + lrow) * NIN + bm0 + lcol,      \
                        &As[b][kr_][0]);                                            \
                GLOAD16(SignF + (size_t)(k0_ + kr_ + lrow) * NIN + bn0 + lcol,      \
                        &Bs[b][kr_][0]);                                            \
            }                                                                       \
        }

    // 16 ascending k; fold every 32 stages (= 512 k, R9-frozen schedule)
    #define ACOMP(s, b)                                                             \
        {                                                                           \
            _Pragma("unroll 4")                                                     \
            for (int k = 0; k < 16; ++k) {                                          \
                const float4 pa = *(const float4*)&As[b][k][ty * 8];                \
                const float4 pb = *(const float4*)&As[b][k][ty * 8 + 4];            \
                const float4 s0 = *(const float4*)&Bs[b][k][tx * 4];                \
                const float4 s1 = *(const float4*)&Bs[b][k][64 + tx * 4];           \
                const float av[8] = {pa.x, pa.y, pa.z, pa.w, pb.x, pb.y, pb.z, pb.w};\
                const float sn[8] = {s0.x, s0.y, s0.z, s0.w, s1.x, s1.y, s1.z, s1.w};\
                _Pragma("unroll")                                                   \
                for (int m = 0; m < 8; ++m)                                         \
                    _Pragma("unroll")                                               \
                    for (int n = 0; n < 8; ++n)                                     \
                        ca[m][n] = fmaf(av[m], sn[n], ca[m][n]);                    \
            }                                                                       \
            if ((((s) + 1) & 31) == 0) {                                            \
                _Pragma("unroll")                                                   \
                for (int m = 0; m < 8; ++m)                                         \
                    _Pragma("unroll")                                               \
                    for (int n = 0; n < 8; ++n) {                                   \
                        ma[m][n] += ca[m][n]; ca[m][n] = 0.f;                       \
                    }                                                               \
            }                                                                       \
        }

    AISSUE(0, 0);
    __syncthreads();   // drains vmcnt: buf0 ready

    for (int s2 = 0; s2 < 128; ++s2) {
        const int s = 2 * s2;
        AISSUE(s + 1, 1);                       // in flight under compute
        ACOMP(s, 0);
        __syncthreads();                        // buf1 ready; all done reading buf0
        if (s + 2 < 256) AISSUE(s + 2, 0);
        ACOMP(s + 1, 1);
        __syncthreads();                        // buf0 ready; all done reading buf1
    }

    // epilogue: r = acid - base (base from ws), np f32 chain (frozen)
    #pragma unroll
    for (int m = 0; m < 8; ++m) {
        const int row = ty * 8 + m;
        const float4 bv0 = *(const float4*)(BaseW + (size_t)(bm0 + row) * NOUT + bn0 + tx * 4);
        const float4 bv1 = *(const float4*)(BaseW + (size_t)(bm0 + row) * NOUT + bn0 + 64 + tx * 4);
        const float bb[8] = {bv0.x, bv0.y, bv0.z, bv0.w, bv1.x, bv1.y, bv1.z, bv1.w};
        float ph[8];
        #pragma unroll
        for (int n = 0; n < 8; ++n) {
            float r    = ma[m][n] - bb[n];
            float conc = fabsf(r) / 409.6f;
            float hc   = (r < 0.f) ? (1e-14f / conc) : conc;
            ph[n]      = (-logf(hc)) / 2.302585092994046f;
        }
        *(float4*)(out + (size_t)(bm0 + row) * NOUT + bn0 + tx * 4) =
            make_float4(ph[0], ph[1], ph[2], ph[3]);
        *(float4*)(out + (size_t)(bm0 + row) * NOUT + bn0 + 64 + tx * 4) =
            make_float4(ph[4], ph[5], ph[6], ph[7]);
    }
    #undef AISSUE
    #undef ACOMP
}

// ================= R18 fused fallback (ws in [134,268) MB) =================
#define LDS_AS0 0
#define LDS_AS1 16384
#define LDS_BS0 32768
#define LDS_BS1 49152
#define LDS_BT0 65536
#define LDS_BT1 73728

__global__ __launch_bounds__(256, 2) void acid_gemm_hyb(const float* __restrict__ AaT,
                                                        const unsigned short* __restrict__ Ab,
                                                        const unsigned short* __restrict__ SignT,
                                                        const float* __restrict__ W,
                                                        float* __restrict__ out) {
    __shared__ __align__(16) char smem[81920];
    float*          As0 = (float*)(smem + LDS_AS0);
    float*          As1 = (float*)(smem + LDS_AS1);
    float*          Bs0 = (float*)(smem + LDS_BS0);
    float*          Bs1 = (float*)(smem + LDS_BS1);
    unsigned short* Bt0 = (unsigned short*)(smem + LDS_BT0);
    unsigned short* Bt1 = (unsigned short*)(smem + LDS_BT1);
    float*          BoutH = (float*)smem;

    const int tid  = threadIdx.x;
    const int tx   = tid & 15;
    const int ty   = tid >> 4;
    const int lane = tid & 63;
    const int wv   = tid >> 6;
    const int g    = lane >> 4;
    const int r16  = lane & 15;
    const int bm0  = blockIdx.y * 128;
    const int bn0  = blockIdx.x * 128;

    float ma[8][8] = {}, ca[8][8] = {};
    f32x4 acc[2][8] = {};
    float4 areg[4];
    float4 wreg[2][2];
    u16x8  btreg[2];

    #define ISSUE_LOADS(s)                                                          \
        {                                                                           \
            const int k0_ = (s) * 32;                                               \
            _Pragma("unroll")                                                       \
            for (int r = 0; r < 4; ++r)                                             \
                areg[r] = *(const float4*)(AaT +                                    \
                    (size_t)(k0_ + (tid >> 3)) * NIN + bm0 + ((tid & 7) + 8 * r) * 4);\
            _Pragma("unroll")                                                       \
            for (int r = 0; r < 2; ++r)                                             \
                _Pragma("unroll")                                                   \
                for (int h = 0; h < 2; ++h)                                         \
                    wreg[r][h] = *(const float4*)(W +                               \
                        (size_t)(k0_ + (tid >> 4) + 16 * r) * NOUT + bn0 + h * 64 + (tid & 15) * 4);\
            _Pragma("unroll")                                                       \
            for (int j = 0; j < 2; ++j)                                             \
                btreg[j] = *(const u16x8*)(SignT +                                  \
                    (size_t)(bn0 + (tid >> 1)) * NIN + k0_ + ((tid & 1) * 2 + j) * 8);\
        }

    #define WRITE_LDS(asp, bsp, btp)                                                \
        {                                                                           \
            _Pragma("unroll")                                                       \
            for (int r = 0; r < 4; ++r)                                             \
                *(float4*)&(asp)[(tid >> 3) * 128 + ((tid & 7) + 8 * r) * 4] = areg[r];\
            _Pragma("unroll")                                                       \
            for (int r = 0; r < 2; ++r)                                             \
                _Pragma("unroll")                                                   \
                for (int h = 0; h < 2; ++h) {                                       \
                    float4 w_ = wreg[r][h];                                         \
                    *(float4*)&(bsp)[((tid >> 4) + 16 * r) * 128 + h * 64 + (tid & 15) * 4] = \
                        make_float4(signf_of(w_.x), signf_of(w_.y),                 \
                                    signf_of(w_.z), signf_of(w_.w));                \
                }                                                                   \
            {                                                                       \
                int row_ = tid >> 1;                                                \
                _Pragma("unroll")                                                   \
                for (int j = 0; j < 2; ++j) {                                       \
                    int c_ = (tid & 1) * 2 + j;                                     \
                    int cs_ = c_ ^ (row_ & 3);                                      \
                    *(u16x8*)&(btp)[row_ * 32 + cs_ * 8] = btreg[j];                \
                }                                                                   \
            }                                                                       \
        }

    #define STAGE(s, ASc, BSc, BTc, ASn, BSn, BTn)                                  \
        {                                                                           \
            const int k0c_ = (s) * 32;                                              \
            bf16x8 af0 = *(const bf16x8*)(Ab +                                      \
                (size_t)(bm0 + wv * 32 + r16) * NIN + k0c_ + g * 8);                \
            bf16x8 af1 = *(const bf16x8*)(Ab +                                      \
                (size_t)(bm0 + wv * 32 + 16 + r16) * NIN + k0c_ + g * 8);           \
            if ((s) + 1 < NSTAGE32) WRITE_LDS(ASn, BSn, BTn);                       \
            if ((s) + 2 < NSTAGE32) ISSUE_LOADS((s) + 2);                           \
            _Pragma("unroll")                                                       \
            for (int tc = 0; tc < 8; ++tc) {                                        \
                int row_ = tc * 16 + r16;                                           \
                int cs_ = g ^ (row_ & 3);                                           \
                bf16x8 bf = *(const bf16x8*)&(BTc)[row_ * 32 + cs_ * 8];            \
                acc[0][tc] = __builtin_amdgcn_mfma_f32_16x16x32_bf16(af0, bf, acc[0][tc], 0, 0, 0);\
                acc[1][tc] = __builtin_amdgcn_mfma_f32_16x16x32_bf16(af1, bf, acc[1][tc], 0, 0, 0);\
            }                                                                       \
            _Pragma("unroll 4")                                                     \
            for (int k = 0; k < 32; ++k) {                                          \
                const float4 pa = *(const float4*)&(ASc)[k * 128 + ty * 8];         \
                const float4 pb = *(const float4*)&(ASc)[k * 128 + ty * 8 + 4];     \
                const float4 s0 = *(const float4*)&(BSc)[k * 128 + tx * 4];         \
                const float4 s1 = *(const float4*)&(BSc)[k * 128 + 64 + tx * 4];    \
                const float av[8] = {pa.x, pa.y, pa.z, pa.w, pb.x, pb.y, pb.z, pb.w};\
                const float sn[8] = {s0.x, s0.y, s0.z, s0.w, s1.x, s1.y, s1.z, s1.w};\
                _Pragma("unroll")                                                   \
                for (int m = 0; m < 8; ++m)                                         \
                    _Pragma("unroll")                                               \
                    for (int n = 0; n < 8; ++n)                                     \
                        ca[m][n] = fmaf(av[m], sn[n], ca[m][n]);                    \
            }                                                                       \
            if ((((s) + 1) & 15) == 0) {                                            \
                _Pragma("unroll")                                                   \
                for (int m = 0; m < 8; ++m)                                         \
                    _Pragma("unroll")                                               \
                    for (int n = 0; n < 8; ++n) {                                   \
                        ma[m][n] += ca[m][n]; ca[m][n] = 0.f;                       \
                    }                                                               \
            }                                                                       \
            __syncthreads();                                                        \
        }

    ISSUE_LOADS(0);
    WRITE_LDS(As0, Bs0, Bt0);
    ISSUE_LOADS(1);
    __syncthreads();

    for (int s2 = 0; s2 < NSTAGE32 / 2; ++s2) {
        STAGE(2 * s2,     As0, Bs0, Bt0, As1, Bs1, Bt1);
        STAGE(2 * s2 + 1, As1, Bs1, Bt1, As0, Bs0, Bt0);
    }

    #pragma unroll
    for (int hh = 0; hh < 2; ++hh) {
        #pragma unroll
        for (int tr = 0; tr < 2; ++tr)
            #pragma unroll
            for (int tc = 0; tc < 4; ++tc)
                #pragma unroll
                for (int rr = 0; rr < 4; ++rr)
                    BoutH[(wv * 32 + tr * 16 + g * 4 + rr) * 68 + tc * 16 + r16] =
                        acc[tr][hh * 4 + tc][rr];
        __syncthreads();
        #pragma unroll
        for (int m = 0; m < 8; ++m) {
            int row = ty * 8 + m;
            const float4 bv = *(const float4*)&BoutH[row * 68 + tx * 4];
            const float bb[4] = {bv.x, bv.y, bv.z, bv.w};
            #pragma unroll
            for (int n = 0; n < 4; ++n) {
                float r    = ma[m][hh * 4 + n] - bb[n];
                float conc = fabsf(r) / 409.6f;
                float hc   = (r < 0.f) ? (1e-14f / conc) : conc;
                float ph   = (-logf(hc)) / 2.302585092994046f;
                out[(size_t)(bm0 + row) * NOUT + bn0 + hh * 64 + tx * 4 + n] = ph;
            }
        }
        __syncthreads();
    }
    #undef ISSUE_LOADS
    #undef WRITE_LDS
    #undef STAGE
}

// Fallback (ws tiny): R9's proven all-VALU kernel, on-the-fly terms.
__global__ __launch_bounds__(256, 2) void acid_gemm_fly(const float* __restrict__ X,
                                                        const float* __restrict__ W,
                                                        float* __restrict__ out) {
    __shared__ float2 Asf[32][128 + 2];
    __shared__ float  Bsf[32][64];
    const int tid = threadIdx.x;
    const int tx = tid & 15, ty = tid >> 4;
    const int bm0 = blockIdx.y * 128, bn0 = blockIdx.x * 64;
    float ma[8][4] = {}, mb[8][4] = {}, ca[8][4] = {}, cb[8][4] = {};
    for (int s = 0; s < NSTAGE32; ++s) {
        const int k0 = s * 32;
        for (int idx = tid; idx < 128 * 32; idx += 256) {
            int m = idx >> 5, k = idx & 31;
            Asf[k][m] = compute_terms(X[(size_t)(bm0 + m) * NIN + k0 + k]);
        }
        for (int idx = tid; idx < 32 * 64; idx += 256) {
            int k = idx >> 6, c = idx & 63;
            Bsf[k][c] = signf_of(W[(size_t)(k0 + k) * NOUT + bn0 + c]);
        }
        __syncthreads();
        #pragma unroll 4
        for (int k = 0; k < 32; ++k) {
            float2 av[8]; float sv[4];
            #pragma unroll
            for (int m = 0; m < 8; ++m) av[m] = Asf[k][ty * 8 + m];
            #pragma unroll
            for (int n = 0; n < 4; ++n) sv[n] = Bsf[k][tx * 4 + n];
            #pragma unroll
            for (int m = 0; m < 8; ++m)
                #pragma unroll
                for (int n = 0; n < 4; ++n) {
                    ca[m][n] = fmaf(av[m].x, sv[n], ca[m][n]);
                    cb[m][n] = fmaf(av[m].y, sv[n], cb[m][n]);
                }
        }
        if (((s + 1) & 15) == 0) {
            #pragma unroll
            for (int m = 0; m < 8; ++m)
                #pragma unroll
                for (int n = 0; n < 4; ++n) {
                    ma[m][n] += ca[m][n]; ca[m][n] = 0.f;
                    mb[m][n] += cb[m][n]; cb[m][n] = 0.f;
                }
        }
        __syncthreads();
    }
    #pragma unroll
    for (int m = 0; m < 8; ++m) {
        int row = bm0 + ty * 8 + m;
        #pragma unroll
        for (int n = 0; n < 4; ++n) {
            int col = bn0 + tx * 4 + n;
            float r = ma[m][n] - mb[m][n];
            float conc = fabsf(r) / 409.6f;
            float hc = (r < 0.f) ? (1e-14f / conc) : conc;
            out[(size_t)row * NOUT + col] = (-logf(hc)) / 2.302585092994046f;
        }
    }
}

extern "C" void kernel_launch(void* const* d_in, const int* in_sizes, int n_in,
                              void* d_out, int out_size, void* d_ws, size_t ws_size,
                              hipStream_t stream) {
    const float* x = (const float*)d_in[0];
    const float* w = (const float*)d_in[1];
    float* out = (float*)d_out;

    const size_t nElem = (size_t)BATCH * NIN;
    // ws layout: AaT f32 | Ab u16 | signT u16 | signF f32 | base f32  = 16 B/elem
    float*          aaT   = (float*)d_ws;
    unsigned short* ab    = (unsigned short*)((char*)d_ws + nElem * 4);
    unsigned short* signT = (unsigned short*)((char*)d_ws + nElem * 6);
    float*          signF = (float*)((char*)d_ws + nElem * 8);
    float*          baseW = (float*)((char*)d_ws + nElem * 12);

    if (ws_size >= nElem * 16) {
        precompute_A     <<<dim3(64, 64), 256, 0, stream>>>(x, aaT, ab);
        precompute_signTF<<<dim3(64, 64), 256, 0, stream>>>(w, signT, signF);
        base_gemm        <<<dim3(32, 32), 256, 0, stream>>>(ab, signT, baseW);
        acid_gemm_valu   <<<dim3(32, 32), 256, 0, stream>>>(aaT, signF, baseW, out);
    } else if (ws_size >= nElem * 8) {
        // R18 fused path (AaT + Ab + signT only); reuse signTF with signF->AaT? No:
        // run the bf16-only transpose via signTF writing signF into AaT's space is
        // unsafe; instead reuse full signTF with a scratch signF inside Ab? Simplest:
        // signF fits nowhere -> use hyb which doesn't need signF.
        precompute_A     <<<dim3(64, 64), 256, 0, stream>>>(x, aaT, ab);
        precompute_signTF<<<dim3(64, 64), 256, 0, stream>>>(w, signT, aaT /*dummy overwritten below*/);
        // NOTE: signTF wrote signF into aaT's buffer; rerun precompute_A to restore AaT.
        precompute_A     <<<dim3(64, 64), 256, 0, stream>>>(x, aaT, ab);
        acid_gemm_hyb    <<<dim3(32, 32), 256, 0, stream>>>(aaT, ab, signT, w, out);
    } else {
        acid_gemm_fly<<<dim3(NOUT / 64, BATCH / 128), dim3(256), 0, stream>>>(x, w, out);
    }
}

// Round 20
// 2000.760 us; speedup vs baseline: 1.1183x; 1.1183x over previous
//
#include <hip/hip_runtime.h>
#include <math.h>

#define BATCH 4096
#define NIN   4096
#define NOUT  4096
// R9-verified ACID ORDER (frozen): [512x8] k-panels, single ascending fmaf
// chain, fold every 512 k, f32 epilogue. BASE on MFMA pipe (R13/R19-verified).
// R20: base MFMA fused into acid kernel TAIL (ca dead -> acc reuses budget;
// per-block tails overlap other blocks' VALU loops, m114). baseW round-trip
// eliminated; precomputes merged into one dispatch.

typedef __attribute__((ext_vector_type(8))) short bf16x8;
typedef __attribute__((ext_vector_type(8))) unsigned short u16x8;
typedef __attribute__((ext_vector_type(4))) float f32x4;

__device__ __forceinline__ float2 compute_terms(float xv) {
    float h  = (float)exp10(-(double)xv);
    float oh = 1e-14f / h;
    return make_float2(h * 0.1f, oh * 0.1f);
}
__device__ __forceinline__ unsigned short bf16_rne(float v) {
    unsigned int b = __float_as_uint(v);
    return (unsigned short)((b + 0x7FFFu + ((b >> 16) & 1u)) >> 16);
}
__device__ __forceinline__ float signf_of(float wv) {
    return (wv > 0.f) ? 1.f : ((wv < 0.f) ? -1.f : 0.f);
}
__device__ __forceinline__ unsigned short signbf16_of(float wv) {
    return (wv > 0.f) ? 0x3F80u : ((wv < 0.f) ? 0xBF80u : 0u);
}

#define GLOAD16(g, l)                                                        \
    __builtin_amdgcn_global_load_lds(                                        \
        (const __attribute__((address_space(1))) void*)(g),                  \
        (__attribute__((address_space(3))) void*)(l), 16, 0, 0)

// --- merged precompute: blocks y<64 process x -> AaT[k][m] f32 + Ab[m][k] bf16;
//     blocks y>=64 process w -> signT[n][k] bf16 + signF[k][n] f32 ---
__global__ __launch_bounds__(256) void precompute_all(const float* __restrict__ x,
                                                      const float* __restrict__ w,
                                                      float* __restrict__ aaT,
                                                      unsigned short* __restrict__ ab,
                                                      unsigned short* __restrict__ sT,
                                                      float* __restrict__ sF) {
    const int tid = threadIdx.x;
    if (blockIdx.y < 64) {
        __shared__ float tile[64][65];
        const int m0 = blockIdx.y * 64, k0 = blockIdx.x * 64;
        #pragma unroll
        for (int it = 0; it < 4; ++it) {
            int idx = tid + it * 256;
            int row = idx >> 4, q = idx & 15;
            float4 xv = *(const float4*)(x + (size_t)(m0 + row) * NIN + k0 + q * 4);
            float2 t0 = compute_terms(xv.x), t1 = compute_terms(xv.y),
                   t2 = compute_terms(xv.z), t3 = compute_terms(xv.w);
            *(ushort4*)(ab + (size_t)(m0 + row) * NIN + k0 + q * 4) =
                make_ushort4(bf16_rne(t0.y), bf16_rne(t1.y), bf16_rne(t2.y), bf16_rne(t3.y));
            tile[row][q * 4 + 0] = t0.x; tile[row][q * 4 + 1] = t1.x;
            tile[row][q * 4 + 2] = t2.x; tile[row][q * 4 + 3] = t3.x;
        }
        __syncthreads();
        #pragma unroll
        for (int it = 0; it < 4; ++it) {
            int idx = tid + it * 256;
            int krow = idx >> 4, q = idx & 15;
            float4 v = make_float4(tile[q * 4 + 0][krow], tile[q * 4 + 1][krow],
                                   tile[q * 4 + 2][krow], tile[q * 4 + 3][krow]);
            *(float4*)(aaT + (size_t)(k0 + krow) * NIN + m0 + q * 4) = v;
        }
    } else {
        __shared__ unsigned short tileu[64][68];
        const int k0 = (blockIdx.y - 64) * 64, n0 = blockIdx.x * 64;
        #pragma unroll
        for (int it = 0; it < 4; ++it) {
            int idx = tid + it * 256;
            int krow = idx >> 4, q = idx & 15;
            float4 wv = *(const float4*)(w + (size_t)(k0 + krow) * NOUT + n0 + q * 4);
            *(ushort4*)&tileu[krow][q * 4] =
                make_ushort4(signbf16_of(wv.x), signbf16_of(wv.y), signbf16_of(wv.z), signbf16_of(wv.w));
            *(float4*)(sF + (size_t)(k0 + krow) * NOUT + n0 + q * 4) =
                make_float4(signf_of(wv.x), signf_of(wv.y), signf_of(wv.z), signf_of(wv.w));
        }
        __syncthreads();
        #pragma unroll
        for (int it = 0; it < 2; ++it) {
            int idx = tid + it * 256;
            int n = idx >> 3, kc = idx & 7;
            u16x8 v;
            #pragma unroll
            for (int j = 0; j < 8; ++j) v[j] = tileu[kc * 8 + j][n];
            *(u16x8*)(sT + (size_t)(n0 + n) * NIN + k0 + kc * 8) = v;
        }
    }
}

// --- fused kernel: acid VALU main loop (R19-verified) + base MFMA tail ---
// LDS: As[2][16][128] + Bs[2][16][128] f32 = 32768 B, aliased by
// BoutH[128][68] f32 = 34816 B in the tail -> block LDS = 34816.
// Regs: main loop ca+ma (ma->AGPR, R19: VGPR 84); tail acc reuses ca's
// budget (ca dead after last fold) -> peak ~150 <= 170 for 3 waves/SIMD.
__global__ __launch_bounds__(256, 3) void acid_base_fused(const float* __restrict__ AaT,
                                                          const float* __restrict__ SignF,
                                                          const unsigned short* __restrict__ Ab,
                                                          const unsigned short* __restrict__ SignT,
                                                          float* __restrict__ out) {
    __shared__ __align__(16) char smem[34816];
    float (*As)[16][128] = (float (*)[16][128])smem;            // [2][16][128]
    float (*Bs)[16][128] = (float (*)[16][128])(smem + 16384);  // [2][16][128]
    float (*BoutH)[68]   = (float (*)[68])smem;                 // [128][68] tail alias

    const int tid = threadIdx.x;
    const int tx  = tid & 15;      // cols tx*4..+3 and 64+tx*4..+3
    const int ty  = tid >> 4;      // rows ty*8..+7
    const int w   = tid >> 6;      // wave
    const int l   = tid & 63;
    const int g   = l >> 4;        // MFMA k-group
    const int r16 = l & 15;
    const int bm0 = blockIdx.y * 128;
    const int bn0 = blockIdx.x * 128;

    const int lrow = (l >> 5);       // sub-row within a 1024B glds
    const int lcol = (l & 31) * 4;   // f32 col within 128-wide row

    float ma[8][8] = {}, ca[8][8] = {};

    #define AISSUE(s, b)                                                            \
        {                                                                           \
            const int k0_ = (s) * 16;                                               \
            _Pragma("unroll")                                                       \
            for (int j = 0; j < 2; ++j) {                                           \
                const int kr_ = w * 4 + 2 * j;                                      \
                GLOAD16(AaT   + (size_t)(k0_ + kr_ + lrow) * NIN + bm0 + lcol,      \
                        &As[b][kr_][0]);                                            \
                GLOAD16(SignF + (size_t)(k0_ + kr_ + lrow) * NIN + bn0 + lcol,      \
                        &Bs[b][kr_][0]);                                            \
            }                                                                       \
        }

    #define ACOMP(s, b)                                                             \
        {                                                                           \
            _Pragma("unroll 4")                                                     \
            for (int k = 0; k < 16; ++k) {                                          \
                const float4 pa = *(const float4*)&As[b][k][ty * 8];                \
                const float4 pb = *(const float4*)&As[b][k][ty * 8 + 4];            \
                const float4 s0 = *(const float4*)&Bs[b][k][tx * 4];                \
                const float4 s1 = *(const float4*)&Bs[b][k][64 + tx * 4];           \
                const float av[8] = {pa.x, pa.y, pa.z, pa.w, pb.x, pb.y, pb.z, pb.w};\
                const float sn[8] = {s0.x, s0.y, s0.z, s0.w, s1.x, s1.y, s1.z, s1.w};\
                _Pragma("unroll")                                                   \
                for (int m = 0; m < 8; ++m)                                         \
                    _Pragma("unroll")                                               \
                    for (int n = 0; n < 8; ++n)                                     \
                        ca[m][n] = fmaf(av[m], sn[n], ca[m][n]);                    \
            }                                                                       \
            if ((((s) + 1) & 31) == 0) {                                            \
                _Pragma("unroll")                                                   \
                for (int m = 0; m < 8; ++m)                                         \
                    _Pragma("unroll")                                               \
                    for (int n = 0; n < 8; ++n) {                                   \
                        ma[m][n] += ca[m][n]; ca[m][n] = 0.f;                       \
                    }                                                               \
            }                                                                       \
        }

    AISSUE(0, 0);
    __syncthreads();   // buf0 ready

    for (int s2 = 0; s2 < 128; ++s2) {
        const int s = 2 * s2;
        AISSUE(s + 1, 1);
        ACOMP(s, 0);
        __syncthreads();
        if (s + 2 < 256) AISSUE(s + 2, 0);
        ACOMP(s + 1, 1);
        __syncthreads();
    }

    // ---- base MFMA tail (R19 base_gemm loop, verified): acc reuses ca's budget ----
    f32x4 acc[2][8] = {};
    {
        const unsigned short* a0 = Ab + (size_t)(bm0 + w * 32 + r16) * NIN + g * 8;
        const unsigned short* a1 = Ab + (size_t)(bm0 + w * 32 + 16 + r16) * NIN + g * 8;
        #pragma unroll 4
        for (int s = 0; s < 128; ++s) {
            const int k0 = s * 32;
            bf16x8 af0 = *(const bf16x8*)(a0 + k0);
            bf16x8 af1 = *(const bf16x8*)(a1 + k0);
            #pragma unroll
            for (int tc = 0; tc < 8; ++tc) {
                bf16x8 bf = *(const bf16x8*)(SignT + (size_t)(bn0 + tc * 16 + r16) * NIN + k0 + g * 8);
                acc[0][tc] = __builtin_amdgcn_mfma_f32_16x16x32_bf16(af0, bf, acc[0][tc], 0, 0, 0);
                acc[1][tc] = __builtin_amdgcn_mfma_f32_16x16x32_bf16(af1, bf, acc[1][tc], 0, 0, 0);
            }
        }
    }

    // ---- combine + epilogue, two column halves (R18/R19-verified) ----
    __syncthreads();   // As/Bs dead; BoutH alias safe
    #pragma unroll
    for (int hh = 0; hh < 2; ++hh) {
        #pragma unroll
        for (int tr = 0; tr < 2; ++tr)
            #pragma unroll
            for (int tc = 0; tc < 4; ++tc)
                #pragma unroll
                for (int rr = 0; rr < 4; ++rr)
                    BoutH[w * 32 + tr * 16 + g * 4 + rr][tc * 16 + r16] = acc[tr][hh * 4 + tc][rr];
        __syncthreads();
        #pragma unroll
        for (int m = 0; m < 8; ++m) {
            const int row = ty * 8 + m;
            const float4 bv = *(const float4*)&BoutH[row][tx * 4];
            const float bb[4] = {bv.x, bv.y, bv.z, bv.w};
            float ph[4];
            #pragma unroll
            for (int n = 0; n < 4; ++n) {
                float r    = ma[m][hh * 4 + n] - bb[n];
                float conc = fabsf(r) / 409.6f;
                float hc   = (r < 0.f) ? (1e-14f / conc) : conc;
                ph[n]      = (-logf(hc)) / 2.302585092994046f;
            }
            *(float4*)(out + (size_t)(bm0 + row) * NOUT + bn0 + hh * 64 + tx * 4) =
                make_float4(ph[0], ph[1], ph[2], ph[3]);
        }
        __syncthreads();
    }
    #undef AISSUE
    #undef ACOMP
}

// Fallback (ws too small): R9's proven all-VALU kernel, on-the-fly terms.
__global__ __launch_bounds__(256, 2) void acid_gemm_fly(const float* __restrict__ X,
                                                        const float* __restrict__ W,
                                                        float* __restrict__ out) {
    __shared__ float2 Asf[32][128 + 2];
    __shared__ float  Bsf[32][64];
    const int tid = threadIdx.x;
    const int tx = tid & 15, ty = tid >> 4;
    const int bm0 = blockIdx.y * 128, bn0 = blockIdx.x * 64;
    float ma[8][4] = {}, mb[8][4] = {}, ca[8][4] = {}, cb[8][4] = {};
    for (int s = 0; s < 128; ++s) {
        const int k0 = s * 32;
        for (int idx = tid; idx < 128 * 32; idx += 256) {
            int m = idx >> 5, k = idx & 31;
            Asf[k][m] = compute_terms(X[(size_t)(bm0 + m) * NIN + k0 + k]);
        }
        for (int idx = tid; idx < 32 * 64; idx += 256) {
            int k = idx >> 6, c = idx & 63;
            Bsf[k][c] = signf_of(W[(size_t)(k0 + k) * NOUT + bn0 + c]);
        }
        __syncthreads();
        #pragma unroll 4
        for (int k = 0; k < 32; ++k) {
            float2 av[8]; float sv[4];
            #pragma unroll
            for (int m = 0; m < 8; ++m) av[m] = Asf[k][ty * 8 + m];
            #pragma unroll
            for (int n = 0; n < 4; ++n) sv[n] = Bsf[k][tx * 4 + n];
            #pragma unroll
            for (int m = 0; m < 8; ++m)
                #pragma unroll
                for (int n = 0; n < 4; ++n) {
                    ca[m][n] = fmaf(av[m].x, sv[n], ca[m][n]);
                    cb[m][n] = fmaf(av[m].y, sv[n], cb[m][n]);
                }
        }
        if (((s + 1) & 15) == 0) {
            #pragma unroll
            for (int m = 0; m < 8; ++m)
                #pragma unroll
                for (int n = 0; n < 4; ++n) {
                    ma[m][n] += ca[m][n]; ca[m][n] = 0.f;
                    mb[m][n] += cb[m][n]; cb[m][n] = 0.f;
                }
        }
        __syncthreads();
    }
    #pragma unroll
    for (int m = 0; m < 8; ++m) {
        int row = bm0 + ty * 8 + m;
        #pragma unroll
        for (int n = 0; n < 4; ++n) {
            int col = bn0 + tx * 4 + n;
            float r = ma[m][n] - mb[m][n];
            float conc = fabsf(r) / 409.6f;
            float hc = (r < 0.f) ? (1e-14f / conc) : conc;
            out[(size_t)row * NOUT + col] = (-logf(hc)) / 2.302585092994046f;
        }
    }
}

extern "C" void kernel_launch(void* const* d_in, const int* in_sizes, int n_in,
                              void* d_out, int out_size, void* d_ws, size_t ws_size,
                              hipStream_t stream) {
    const float* x = (const float*)d_in[0];
    const float* w = (const float*)d_in[1];
    float* out = (float*)d_out;

    const size_t nElem = (size_t)BATCH * NIN;
    // ws layout: AaT f32 | Ab u16 | signT u16 | signF f32  = 12 B/elem (201 MB)
    float*          aaT   = (float*)d_ws;
    unsigned short* ab    = (unsigned short*)((char*)d_ws + nElem * 4);
    unsigned short* signT = (unsigned short*)((char*)d_ws + nElem * 6);
    float*          signF = (float*)((char*)d_ws + nElem * 8);

    if (ws_size >= nElem * 12) {
        precompute_all <<<dim3(64, 128), 256, 0, stream>>>(x, w, aaT, ab, signT, signF);
        acid_base_fused<<<dim3(32, 32), 256, 0, stream>>>(aaT, signF, ab, signT, out);
    } else {
        acid_gemm_fly<<<dim3(NOUT / 64, BATCH / 128), dim3(256), 0, stream>>>(x, w, out);
    }
}